// Round 1
// baseline (208.795 us; speedup 1.0000x reference)
//
#include <hip/hip_runtime.h>

// Problem constants (fixed by the reference setup_inputs)
#define N_PTS 8192   // points per batch
#define M_Q   2048   // query points per batch
#define C_F   64     // feature channels
#define NS    32     // nsample
#define B_SZ  8      // batch

// ---------------------------------------------------------------------------
// Workspace layout (ws >= 21 MB per previous session; we use 8 MB):
//   xyz4  : B*N float4  @ 0     (1 MB)   (x,y,z,p2) p2 in exact np.sum order
//   xyzT  : B*3*N float @ 2 MB  (768 KB) component planes for c<3 gather
//   nxyzT : B*3*M float @ 4 MB  (192 KB) query component planes
//   gidx  : B*M*NS int  @ 6 MB  (2 MB)   ball-query indices
// ---------------------------------------------------------------------------

// K1: prep. i in [0, B*N): xyz4 + xyzT planes. i in [B*N, B*N+B*M): nxyzT.
// p2sum computed in the exact numpy f32 order ((x*x+y*y)+z*z), contract OFF —
// feeds the pinned d2 formula bit-for-bit (unchanged from verified kernel).
__global__ __launch_bounds__(256) void prep_kernel(
    const float* __restrict__ xyz, const float* __restrict__ nxyz,
    float4* __restrict__ xyz4, float* __restrict__ xyzT,
    float* __restrict__ nxyzT)
{
#pragma clang fp contract(off)
    const int i = blockIdx.x * 256 + (int)threadIdx.x;
    if (i < B_SZ * N_PTS) {
        const float p0 = xyz[i * 3 + 0];
        const float p1 = xyz[i * 3 + 1];
        const float p2 = xyz[i * 3 + 2];
        const float s  = (p0 * p0 + p1 * p1) + p2 * p2;   // np.sum order, no fma
        xyz4[i] = make_float4(p0, p1, p2, s);
        const int b = i >> 13;              // / N_PTS
        const int n = i & (N_PTS - 1);
        xyzT[((size_t)b * 3 + 0) * N_PTS + n] = p0;
        xyzT[((size_t)b * 3 + 1) * N_PTS + n] = p1;
        xyzT[((size_t)b * 3 + 2) * N_PTS + n] = p2;
    } else {
        const int j = i - B_SZ * N_PTS;     // < B*M
        const float q0 = nxyz[j * 3 + 0];
        const float q1 = nxyz[j * 3 + 1];
        const float q2 = nxyz[j * 3 + 2];
        const int b = j >> 11;              // / M_Q
        const int m = j & (M_Q - 1);
        nxyzT[((size_t)b * 3 + 0) * M_Q + m] = q0;
        nxyzT[((size_t)b * 3 + 1) * M_Q + m] = q1;
        nxyzT[((size_t)b * 3 + 2) * M_Q + m] = q2;
    }
}

// ---------------------------------------------------------------------------
// K2: ball-query scan. Block = 256 threads = 4 waves = 4 queries; no LDS, no
// barriers — each wave scans independently and writes its 32 indices straight
// to gidx. Heavy-tail waves (~4% scan all 8192 pts) overlap freely across the
// 4096-block grid instead of stalling a fused gather.
// NUMERICS (pinned, previously verified absmax=0): d2 = (q2 + p2sum) - 2*qp,
// all partials left-to-right f32, contract OFF, bit-matching numpy.
// ---------------------------------------------------------------------------
__global__ __launch_bounds__(256) void scan_kernel(
    const float4* __restrict__ xyz4, const float* __restrict__ nxyz,
    int* __restrict__ gidx)
{
#pragma clang fp contract(off)
    const int lane = threadIdx.x & 63;
    const int w    = threadIdx.x >> 6;            // wave id 0..3
    const int q    = blockIdx.x * 4 + w;          // this wave's query
    const int b    = q >> 11;                     // M_Q = 2048
    const float4* __restrict__ xb = xyz4 + (size_t)b * N_PTS;
    int* __restrict__ gout = gidx + (size_t)q * NS;

    const float* __restrict__ qp = nxyz + (size_t)q * 3;
    const float qx = qp[0], qy = qp[1], qz = qp[2];
    const float q2 = (qx * qx + qy * qy) + qz * qz;   // np.sum order

    int  cnt = 0;
    int  first_idx = 0;
    bool have_first = false;

    for (int base = 0; base < N_PTS && cnt < NS; base += 256) {
        float4 P[4];
#pragma unroll
        for (int cc = 0; cc < 4; ++cc)
            P[cc] = xb[base + cc * 64 + lane];
#pragma unroll
        for (int cc = 0; cc < 4; ++cc) {
            if (cnt >= NS) break;                       // wave-uniform
            const float qpdot = (qx * P[cc].x + qy * P[cc].y) + qz * P[cc].z;
            const float d2 = (q2 + P[cc].w) - 2.0f * qpdot;   // ref formula
            const bool pred = d2 < 1.0f;
            const unsigned long long mask = __ballot(pred);
            if (mask) {
                if (!have_first) {
                    first_idx = base + cc * 64 + __ffsll(mask) - 1;
                    have_first = true;
                }
                if (pred) {
                    const int pos = cnt + (int)__popcll(mask & ((1ull << lane) - 1ull));
                    if (pos < NS) gout[pos] = base + cc * 64 + lane;
                }
                cnt += (int)__popcll(mask);
            }
        }
    }
    if (cnt < NS) {
        for (int p = cnt + lane; p < NS; p += 64) gout[p] = first_idx;
    }
}

// ---------------------------------------------------------------------------
// K3: channel-planar gather. feat is (B,C,N) — already planar, so NO featT
// transpose is needed. Block = (b, channel c in [0,67), M-quarter mq).
// Stage the 32 KB plane in LDS; then stream 16 iters of
// {coalesced int4 idx load -> 4 random LDS lookups -> coalesced float4 store}
// into a fully contiguous 64 KB output slice. Uniform work per block.
//
// blockIdx layout pins all 67 channel-blocks of one (b,mq) group to one XCD
// (dispatch round-robins blockIdx%8), so the 67x re-read of each 64 KB idx
// slice stays in that XCD's L2:  blockIdx = ((gid/8)*67 + c)*8 + gid%8,
// gid = b*4+mq in [0,32). Bijective onto [0, 2144).
// ---------------------------------------------------------------------------
__global__ __launch_bounds__(256) void gather_kernel(
    const float* __restrict__ feat, const float* __restrict__ xyzT,
    const float* __restrict__ nxyzT, const int* __restrict__ gidx,
    float* __restrict__ out)
{
#pragma clang fp contract(off)
    __shared__ float plane[N_PTS];    // 32 KB
    __shared__ float qsh[512];        // 2 KB (c<3 only)

    const int x   = blockIdx.x & 7;
    const int t   = blockIdx.x >> 3;
    const int gq  = t / 67;           // 0..3
    const int c   = t % 67;           // output channel
    const int gid = gq * 8 + x;       // 0..31
    const int b   = gid >> 2;
    const int mq  = gid & 3;
    const int m0  = mq * 512;

    const float* __restrict__ src =
        (c < 3) ? (xyzT + ((size_t)b * 3 + c) * N_PTS)
                : (feat + ((size_t)b * C_F + (c - 3)) * N_PTS);

    {   // stage plane: 2048 float4, 8 per thread, coalesced
        const float4* __restrict__ s4 = (const float4*)src;
        float4* p4 = (float4*)plane;
#pragma unroll
        for (int k = 0; k < 8; ++k)
            p4[k * 256 + threadIdx.x] = s4[k * 256 + threadIdx.x];
    }
    if (c < 3) {
        const float* __restrict__ qsrc = nxyzT + ((size_t)b * 3 + c) * M_Q + m0;
        qsh[threadIdx.x]       = qsrc[threadIdx.x];
        qsh[256 + threadIdx.x] = qsrc[256 + threadIdx.x];
    }
    __syncthreads();

    const int* __restrict__ idxp = gidx + ((size_t)b * M_Q + m0) * NS;
    float* __restrict__ op = out + (((size_t)b * 67 + c) * M_Q + m0) * NS;

    // 512 m x 32 s = 4096 float4 slots; e -> (m = e>>3, s4 = (e&7)*4)
    if (c < 3) {
#pragma unroll 4
        for (int it = 0; it < 16; ++it) {
            const int e  = it * 256 + (int)threadIdx.x;
            const int m  = e >> 3;
            const int s4 = (e & 7) * 4;
            const int4 nn = *(const int4*)(idxp + m * NS + s4);
            const float qc = qsh[m];
            float4 v;
            v.x = plane[nn.x] - qc;
            v.y = plane[nn.y] - qc;
            v.z = plane[nn.z] - qc;
            v.w = plane[nn.w] - qc;
            *(float4*)(op + (size_t)m * NS + s4) = v;
        }
    } else {
#pragma unroll 4
        for (int it = 0; it < 16; ++it) {
            const int e  = it * 256 + (int)threadIdx.x;
            const int m  = e >> 3;
            const int s4 = (e & 7) * 4;
            const int4 nn = *(const int4*)(idxp + m * NS + s4);
            float4 v;
            v.x = plane[nn.x];
            v.y = plane[nn.y];
            v.z = plane[nn.z];
            v.w = plane[nn.w];
            *(float4*)(op + (size_t)m * NS + s4) = v;
        }
    }
}

extern "C" void kernel_launch(void* const* d_in, const int* in_sizes, int n_in,
                              void* d_out, int out_size, void* d_ws, size_t ws_size,
                              hipStream_t stream)
{
    const float* xyz  = (const float*)d_in[0];   // (B, N, 3)
    const float* nxyz = (const float*)d_in[1];   // (B, M, 3)
    const float* feat = (const float*)d_in[2];   // (B, C, N)
    float* out = (float*)d_out;                  // (B, 67, M, 32)

    float4* xyz4  = (float4*)d_ws;                            // 1 MB
    float*  xyzT  = (float*)((char*)d_ws + (2u << 20));       // 768 KB
    float*  nxyzT = (float*)((char*)d_ws + (4u << 20));       // 192 KB
    int*    gidx  = (int*)  ((char*)d_ws + (6u << 20));       // 2 MB

    prep_kernel<<<(B_SZ * N_PTS + B_SZ * M_Q) / 256, 256, 0, stream>>>(
        xyz, nxyz, xyz4, xyzT, nxyzT);
    scan_kernel<<<(B_SZ * M_Q) / 4, 256, 0, stream>>>(xyz4, nxyz, gidx);
    gather_kernel<<<B_SZ * 67 * 4, 256, 0, stream>>>(feat, xyzT, nxyzT, gidx, out);
}

// Round 3
// 191.018 us; speedup vs baseline: 1.0931x; 1.0931x over previous
//
#include <hip/hip_runtime.h>

// Problem constants (fixed by the reference setup_inputs)
#define N_PTS 8192   // points per batch
#define M_Q   2048   // query points per batch
#define C_F   64     // feature channels
#define NS    32     // nsample
#define B_SZ  8      // batch

// native clang vector — __builtin_nontemporal_store requires this (HIP's
// float4 is a class and is rejected by the builtin).
typedef float f32x4 __attribute__((ext_vector_type(4)));

// ---------------------------------------------------------------------------
// Workspace layout (uses 4 MB):
//   xyz4 : B*N float4 @ 0    (1 MB)  (x,y,z,p2), p2 in exact np.sum order
//   gidx : B*M*NS int @ 2 MB (2 MB)  ball-query indices
// ---------------------------------------------------------------------------

// K1: prep. xyz4[b*N+n] = (x,y,z,p2). p2 computed in the exact numpy f32
// order ((x*x+y*y)+z*z), contract OFF — feeds the pinned d2 formula
// bit-for-bit (unchanged from the verified kernel).
__global__ __launch_bounds__(256) void prep_kernel(
    const float* __restrict__ xyz, float4* __restrict__ xyz4)
{
#pragma clang fp contract(off)
    const int i = blockIdx.x * 256 + (int)threadIdx.x;   // < B*N
    const float p0 = xyz[i * 3 + 0];
    const float p1 = xyz[i * 3 + 1];
    const float p2 = xyz[i * 3 + 2];
    const float s  = (p0 * p0 + p1 * p1) + p2 * p2;      // np.sum order, no fma
    xyz4[i] = make_float4(p0, p1, p2, s);
}

// ---------------------------------------------------------------------------
// K2: ball-query scan. Block = 256 threads = 4 waves = 4 queries; no LDS, no
// barriers — each wave scans independently, early-exits at 32 hits, and
// writes its indices straight to gidx.
// NUMERICS (pinned, verified absmax=0 across sessions): d2 = (q2+p2) - 2*qp,
// all partials left-to-right f32, contract OFF, bit-matching numpy.
// ---------------------------------------------------------------------------
__global__ __launch_bounds__(256) void scan_kernel(
    const float4* __restrict__ xyz4, const float* __restrict__ nxyz,
    int* __restrict__ gidx)
{
#pragma clang fp contract(off)
    const int lane = threadIdx.x & 63;
    const int w    = threadIdx.x >> 6;            // wave id 0..3
    const int q    = blockIdx.x * 4 + w;          // this wave's query
    const int b    = q >> 11;                     // M_Q = 2048
    const float4* __restrict__ xb = xyz4 + (size_t)b * N_PTS;
    int* __restrict__ gout = gidx + (size_t)q * NS;

    const float* __restrict__ qp = nxyz + (size_t)q * 3;
    const float qx = qp[0], qy = qp[1], qz = qp[2];
    const float q2 = (qx * qx + qy * qy) + qz * qz;   // np.sum order

    int  cnt = 0;
    int  first_idx = 0;
    bool have_first = false;

    for (int base = 0; base < N_PTS && cnt < NS; base += 256) {
        float4 P[4];
#pragma unroll
        for (int cc = 0; cc < 4; ++cc)
            P[cc] = xb[base + cc * 64 + lane];
#pragma unroll
        for (int cc = 0; cc < 4; ++cc) {
            if (cnt >= NS) break;                       // wave-uniform
            const float qpdot = (qx * P[cc].x + qy * P[cc].y) + qz * P[cc].z;
            const float d2 = (q2 + P[cc].w) - 2.0f * qpdot;   // ref formula
            const bool pred = d2 < 1.0f;
            const unsigned long long mask = __ballot(pred);
            if (mask) {
                if (!have_first) {
                    first_idx = base + cc * 64 + __ffsll(mask) - 1;
                    have_first = true;
                }
                if (pred) {
                    const int pos = cnt + (int)__popcll(mask & ((1ull << lane) - 1ull));
                    if (pos < NS) gout[pos] = base + cc * 64 + lane;
                }
                cnt += (int)__popcll(mask);
            }
        }
    }
    if (cnt < NS) {
        for (int p = cnt + lane; p < NS; p += 64) gout[p] = first_idx;
    }
}

// ---------------------------------------------------------------------------
// K3: channel-planar gather. Block = 512 threads, one (b, channel, M-quarter).
// feat is (B,C,N) — already planar, no transpose needed anywhere.
//
// Latency discipline: each thread PREFETCHES its 8 int4 of indices into
// registers (fully unrolled — stays in VGPRs) while the 32 KB channel plane
// stages into LDS. The post-sync loop is then pure {random LDS read ->
// contiguous nontemporal float4 store} — no global-load latency on the
// critical path. 34 KB LDS + 512 thr -> ~3-4 blocks/CU = 24-32 waves/CU.
//
// blockIdx layout pins all 67 channel-blocks of one (b,mq) group to one XCD
// (dispatch round-robins blockIdx%8), so the 67x re-read of each 64 KB idx
// slice stays in that XCD's L2: blockIdx = ((gq*67 + c)*8 + x),
// gid = gq*8 + x in [0,32). Bijective onto [0, 2144).
// ---------------------------------------------------------------------------
__global__ __launch_bounds__(512) void gather_kernel(
    const float* __restrict__ feat, const float* __restrict__ xyz,
    const float* __restrict__ nxyz, const int* __restrict__ gidx,
    float* __restrict__ out)
{
#pragma clang fp contract(off)
    __shared__ float plane[N_PTS];    // 32 KB
    __shared__ float qsh[512];        // 2 KB (c<3 only)

    const int tid = (int)threadIdx.x;
    const int x   = blockIdx.x & 7;
    const int t   = blockIdx.x >> 3;
    const int gq  = t / 67;           // 0..3
    const int c   = t % 67;           // output channel
    const int gid = gq * 8 + x;       // 0..31
    const int b   = gid >> 2;
    const int mq  = gid & 3;
    const int m0  = mq * 512;

    // ---- prefetch this thread's 8 idx-int4 (block slice = 64 KB) ----
    const int* __restrict__ idxp = gidx + ((size_t)b * M_Q + m0) * NS;
    int4 nn[8];
#pragma unroll
    for (int it = 0; it < 8; ++it)
        nn[it] = *(const int4*)(idxp + (it * 512 + tid) * 4);

    // ---- stage the 32 KB channel plane (overlaps the idx loads) ----
    if (c < 3) {
        const float* __restrict__ src = xyz + (size_t)b * N_PTS * 3 + c;
#pragma unroll
        for (int k = 0; k < 16; ++k) {
            const int n = k * 512 + tid;
            plane[n] = src[(size_t)n * 3];
        }
        qsh[tid] = nxyz[((size_t)b * M_Q + m0 + tid) * 3 + c];
    } else {
        const float4* __restrict__ s4p =
            (const float4*)(feat + ((size_t)b * C_F + (c - 3)) * N_PTS);
        float4* p4 = (float4*)plane;
#pragma unroll
        for (int k = 0; k < 4; ++k)
            p4[k * 512 + tid] = s4p[k * 512 + tid];
    }
    __syncthreads();

    // ---- pure LDS->store stream: 4096 float4 slots, 8 per thread ----
    float* __restrict__ op = out + (((size_t)b * 67 + c) * M_Q + m0) * NS;
    if (c < 3) {
#pragma unroll
        for (int it = 0; it < 8; ++it) {
            const int e  = it * 512 + tid;
            const float qc = qsh[e >> 3];
            f32x4 v;
            v.x = plane[nn[it].x] - qc;
            v.y = plane[nn[it].y] - qc;
            v.z = plane[nn[it].z] - qc;
            v.w = plane[nn[it].w] - qc;
            __builtin_nontemporal_store(v, (f32x4*)(op + (size_t)e * 4));
        }
    } else {
#pragma unroll
        for (int it = 0; it < 8; ++it) {
            const int e = it * 512 + tid;
            f32x4 v;
            v.x = plane[nn[it].x];
            v.y = plane[nn[it].y];
            v.z = plane[nn[it].z];
            v.w = plane[nn[it].w];
            __builtin_nontemporal_store(v, (f32x4*)(op + (size_t)e * 4));
        }
    }
}

extern "C" void kernel_launch(void* const* d_in, const int* in_sizes, int n_in,
                              void* d_out, int out_size, void* d_ws, size_t ws_size,
                              hipStream_t stream)
{
    const float* xyz  = (const float*)d_in[0];   // (B, N, 3)
    const float* nxyz = (const float*)d_in[1];   // (B, M, 3)
    const float* feat = (const float*)d_in[2];   // (B, C, N)
    float* out = (float*)d_out;                  // (B, 67, M, 32)

    float4* xyz4 = (float4*)d_ws;                        // 1 MB
    int*    gidx = (int*)((char*)d_ws + (2u << 20));     // 2 MB

    prep_kernel<<<(B_SZ * N_PTS) / 256, 256, 0, stream>>>(xyz, xyz4);
    scan_kernel<<<(B_SZ * M_Q) / 4, 256, 0, stream>>>(xyz4, nxyz, gidx);
    gather_kernel<<<B_SZ * 67 * 4, 512, 0, stream>>>(feat, xyz, nxyz, gidx, out);
}

// Round 4
// 184.237 us; speedup vs baseline: 1.1333x; 1.0368x over previous
//
#include <hip/hip_runtime.h>

// Problem constants (fixed by the reference setup_inputs)
#define N_PTS 8192   // points per batch
#define M_Q   2048   // query points per batch
#define C_F   64     // feature channels
#define NS    32     // nsample
#define B_SZ  8      // batch

// native clang vector — __builtin_nontemporal_store requires this (HIP's
// float4 is a class and is rejected by the builtin).
typedef float f32x4 __attribute__((ext_vector_type(4)));

// ---------------------------------------------------------------------------
// K1: prep (vectorized).
//  blocks [0, 1024):   transpose feat (b,c,n) -> featT (b,n,c). 64x64 tile.
//    Global loads: float4 along n (16 B/lane, 4 segments x 256 B per wave).
//    Global stores: float4 along c — consecutive nn rows are adjacent, so a
//    wave writes 1 KB fully contiguous. LDS row stride 65 floats: scalar
//    writes/reads land <=2-way on banks (free, m136).
//  blocks [1024, 1280): xyz4[b*N+n] = (x, y, z, p2sum). p2sum in the exact
//    numpy f32 order ((x*x+y*y)+z*z), contract OFF — feeds the pinned d2
//    formula bit-for-bit (unchanged from the verified kernel).
// ---------------------------------------------------------------------------
__global__ __launch_bounds__(256) void prep_kernel(
    const float* __restrict__ feat, const float* __restrict__ xyz,
    float* __restrict__ featT, float4* __restrict__ xyz4)
{
#pragma clang fp contract(off)
    __shared__ float lds[C_F * 65];
    if (blockIdx.x < B_SZ * 128) {
        const int b  = blockIdx.x >> 7;        // 128 n-tiles per batch
        const int n0 = (blockIdx.x & 127) * 64;
        {
            const int c_lo = (int)threadIdx.x >> 4;        // 0..15
            const int n4   = ((int)threadIdx.x & 15) * 4;  // 0..60
#pragma unroll
            for (int k = 0; k < 4; ++k) {
                const int c = k * 16 + c_lo;
                const float4 v =
                    *(const float4*)&feat[((size_t)b * C_F + c) * N_PTS + n0 + n4];
                lds[c * 65 + n4 + 0] = v.x;
                lds[c * 65 + n4 + 1] = v.y;
                lds[c * 65 + n4 + 2] = v.z;
                lds[c * 65 + n4 + 3] = v.w;
            }
        }
        __syncthreads();
        {
            const int n_lo = (int)threadIdx.x >> 4;        // 0..15
            const int c0   = ((int)threadIdx.x & 15) * 4;  // 0..60
#pragma unroll
            for (int k = 0; k < 4; ++k) {
                const int nn = k * 16 + n_lo;
                float4 w;
                w.x = lds[(c0 + 0) * 65 + nn];
                w.y = lds[(c0 + 1) * 65 + nn];
                w.z = lds[(c0 + 2) * 65 + nn];
                w.w = lds[(c0 + 3) * 65 + nn];
                *(float4*)&featT[((size_t)b * N_PTS + n0 + nn) * C_F + c0] = w;
            }
        }
    } else {
        const int i = (blockIdx.x - B_SZ * 128) * 256 + (int)threadIdx.x; // 0..B*N-1
        const float p0 = xyz[i * 3 + 0];
        const float p1 = xyz[i * 3 + 1];
        const float p2 = xyz[i * 3 + 2];
        const float s  = (p0 * p0 + p1 * p1) + p2 * p2;   // np.sum order, no fma
        xyz4[i] = make_float4(p0, p1, p2, s);
    }
}

// ---------------------------------------------------------------------------
// K2: fused ball-query + gather. Block = 256 threads = 4 waves = 4 queries.
//
// Scan (per wave): macro-chunks of 256 pts, DOUBLE-BUFFERED — chunk k+1's
// 4 dwordx4 loads are issued before processing chunk k's 4 ballot/compact
// rounds, halving the latency exposure of heavy-tail (full-8192) waves.
// NUMERICS (pinned, verified absmax=0): d2 = (q2 + p2sum) - 2*qp, all
// partials left-to-right f32, contract OFF — byte-identical to r0's code.
//
// Gather (whole block, per query): T14 async-stage split — round w2+1's
// featT row loads (2 float4/thread) + xyz/query loads are issued into
// registers BEFORE round w2's barrier + 536-store stream, hiding the L2/L3
// row-read latency under the stores. Stores are nontemporal (out is never
// re-read; keeps featT/xyz4 lines resident in L2).
// ---------------------------------------------------------------------------
__global__ __launch_bounds__(256) void qbg_kernel(
    const float4* __restrict__ xyz4, const float* __restrict__ nxyz,
    const float* __restrict__ featT, float* __restrict__ out)
{
#pragma clang fp contract(off)
    __shared__ int   sidx[4][NS];
    __shared__ float stage[67 * 33];

    const int lane = threadIdx.x & 63;
    const int w    = threadIdx.x >> 6;            // wave id 0..3
    const int q    = blockIdx.x * 4 + w;          // this wave's query
    const int b    = q >> 11;                     // M_Q = 2048
    const float4* __restrict__ xb = xyz4 + (size_t)b * N_PTS;

    {
        const float* __restrict__ qp = nxyz + (size_t)q * 3;
        const float qx = qp[0], qy = qp[1], qz = qp[2];
        const float q2 = (qx * qx + qy * qy) + qz * qz;   // np.sum order

        int  cnt = 0;
        int  first_idx = 0;
        bool have_first = false;

        float4 P[4], Q[4];
#pragma unroll
        for (int cc = 0; cc < 4; ++cc) P[cc] = xb[cc * 64 + lane];

        for (int base = 0; base < N_PTS && cnt < NS; base += 256) {
            const int nb = base + 256;
            if (nb < N_PTS) {
#pragma unroll
                for (int cc = 0; cc < 4; ++cc) Q[cc] = xb[nb + cc * 64 + lane];
            }
#pragma unroll
            for (int cc = 0; cc < 4; ++cc) {
                if (cnt >= NS) break;                       // wave-uniform
                const float qpdot = (qx * P[cc].x + qy * P[cc].y) + qz * P[cc].z;
                const float d2 = (q2 + P[cc].w) - 2.0f * qpdot;   // ref formula
                const bool pred = d2 < 1.0f;
                const unsigned long long mask = __ballot(pred);
                if (mask) {
                    if (!have_first) {
                        first_idx = base + cc * 64 + __ffsll(mask) - 1;
                        have_first = true;
                    }
                    if (pred) {
                        const int pos = cnt + (int)__popcll(mask & ((1ull << lane) - 1ull));
                        if (pos < NS) sidx[w][pos] = base + cc * 64 + lane;
                    }
                    cnt += (int)__popcll(mask);
                }
            }
#pragma unroll
            for (int cc = 0; cc < 4; ++cc) P[cc] = Q[cc];
        }
        if (cnt < NS) {
            for (int p = cnt + lane; p < NS; p += 64) sidx[w][p] = first_idx;
        }
    }
    __syncthreads();

    // ---- gather phase: 4 queries, sequentially, whole block each ----
    const int pS = threadIdx.x >> 3;              // sample 0..31
    const int j  = threadIdx.x & 7;               // lane-within-sample
    const size_t cstride = (size_t)M_Q * NS;      // 65536

    // prefetch round 0
    float4 va, vb, pv;
    float q0v = 0.f, q1v = 0.f, q2v = 0.f;
    {
        const int n0 = sidx[0][pS];
        const float* __restrict__ fb = featT + ((size_t)b * N_PTS + n0) * C_F;
        va = *(const float4*)(fb + j * 4);
        vb = *(const float4*)(fb + 32 + j * 4);
        if (j == 0) {
            pv = xb[n0];
            const float* __restrict__ qp2 = nxyz + (size_t)(blockIdx.x * 4) * 3;
            q0v = qp2[0]; q1v = qp2[1]; q2v = qp2[2];
        }
    }

    for (int w2 = 0; w2 < 4; ++w2) {
        // stage current round's prefetched registers
        const int ca = j * 4;
        stage[(3 + ca + 0)  * 33 + pS] = va.x;
        stage[(3 + ca + 1)  * 33 + pS] = va.y;
        stage[(3 + ca + 2)  * 33 + pS] = va.z;
        stage[(3 + ca + 3)  * 33 + pS] = va.w;
        stage[(35 + ca + 0) * 33 + pS] = vb.x;
        stage[(35 + ca + 1) * 33 + pS] = vb.y;
        stage[(35 + ca + 2) * 33 + pS] = vb.z;
        stage[(35 + ca + 3) * 33 + pS] = vb.w;
        if (j == 0) {
            stage[0 * 33 + pS] = pv.x - q0v;
            stage[1 * 33 + pS] = pv.y - q1v;
            stage[2 * 33 + pS] = pv.z - q2v;
        }

        // issue next round's loads (overlap barrier + store stream)
        float4 van, vbn, pvn;
        float q0n = 0.f, q1n = 0.f, q2n = 0.f;
        if (w2 < 3) {
            const int nx = sidx[w2 + 1][pS];
            const float* __restrict__ fb = featT + ((size_t)b * N_PTS + nx) * C_F;
            van = *(const float4*)(fb + j * 4);
            vbn = *(const float4*)(fb + 32 + j * 4);
            if (j == 0) {
                pvn = xb[nx];
                const float* __restrict__ qp2 =
                    nxyz + (size_t)(blockIdx.x * 4 + w2 + 1) * 3;
                q0n = qp2[0]; q1n = qp2[1]; q2n = qp2[2];
            }
        }
        __syncthreads();

        // 67 rows x 8 float4 = 536 nontemporal vector stores
        const int qq = blockIdx.x * 4 + w2;
        const int mm = qq & (M_Q - 1);
        const size_t obase = ((size_t)b * 67 * M_Q + mm) * NS;
#pragma unroll
        for (int it = 0; it < 3; ++it) {
            const int e = it * 256 + (int)threadIdx.x;
            if (e < 67 * 8) {
                const int row  = e >> 3;
                const int col4 = (e & 7) * 4;
                f32x4 v;
                v.x = stage[row * 33 + col4 + 0];
                v.y = stage[row * 33 + col4 + 1];
                v.z = stage[row * 33 + col4 + 2];
                v.w = stage[row * 33 + col4 + 3];
                __builtin_nontemporal_store(
                    v, (f32x4*)&out[obase + (size_t)row * cstride + col4]);
            }
        }
        __syncthreads();   // stage reused next round

        va = van; vb = vbn; pv = pvn;
        q0v = q0n; q1v = q1n; q2v = q2n;
    }
}

extern "C" void kernel_launch(void* const* d_in, const int* in_sizes, int n_in,
                              void* d_out, int out_size, void* d_ws, size_t ws_size,
                              hipStream_t stream)
{
    const float* xyz  = (const float*)d_in[0];   // (B, N, 3)
    const float* nxyz = (const float*)d_in[1];   // (B, M, 3)
    const float* feat = (const float*)d_in[2];   // (B, C, N)
    float* out = (float*)d_out;                  // (B, 67, M, 32)

    float*  featT = (float*)d_ws;                             // 16.8 MB
    float4* xyz4  = (float4*)((char*)d_ws + (20 << 20));      // 1 MB

    const int Q = B_SZ * M_Q;                    // 16384 queries

    prep_kernel<<<B_SZ * 128 + (B_SZ * N_PTS) / 256, 256, 0, stream>>>(
        feat, xyz, featT, xyz4);
    qbg_kernel<<<Q / 4, 256, 0, stream>>>(xyz4, nxyz, featT, out);
}